// Round 1
// baseline (516.274 us; speedup 1.0000x reference)
//
#include <hip/hip_runtime.h>
#include <math.h>

// Problem constants (fixed by the reference setup)
#define NNODE 32768     // B*T*N
#define NEDGE 524288    // NNODE * DEG
#define DD 64           // feature dim D
#define NPER 4096       // atoms per structure (N)

__device__ __forceinline__ float silu_f(float x) {
    return x / (1.0f + __expf(-x));
}

// pos = x * v_mask + x1 * (1 - v_mask)
__global__ __launch_bounds__(256) void k_prep(
    const float* __restrict__ x, const float* __restrict__ x1,
    const float* __restrict__ vm, float* __restrict__ pos)
{
    int i = blockIdx.x * blockDim.x + threadIdx.x;
    if (i < NNODE) {
        float m = vm[i];
        #pragma unroll
        for (int c = 0; c < 3; ++c)
            pos[i*3+c] = x[i*3+c]*m + x1[i*3+c]*(1.0f-m);
    }
}

// Edge kernel. One wave (64 lanes) per edge iteration; lane d owns channel d.
// PASS==1: accumulate agg[dst][d] += msg[d]
// PASS==2: dot = sum_d msg[d]*g[dst][d]; outacc[dst][c] += ev[c]*dot
template<int PASS>
__global__ __launch_bounds__(256) void k_edge(
    const int* __restrict__ ei, const int* __restrict__ tj,
    const float* __restrict__ pos, const float* __restrict__ cell,
    const float* __restrict__ t, const float* __restrict__ Wsp,
    const float* __restrict__ Wt, const float* __restrict__ We,
    const float* __restrict__ Wm,
    float* agg,              // pass1 out (also gate buffer input in pass2)
    const float* gbuf,       // pass2 in
    float* outacc)           // pass2 out
{
    const int lane = threadIdx.x & 63;
    const int wid  = (blockIdx.x * (blockDim.x >> 6)) + (threadIdx.x >> 6);
    const int nw   = gridDim.x * (blockDim.x >> 6);

    // W_msg rows 128..191 (the "ea" block), column `lane`, held in VGPRs.
    float w3c[DD];
    #pragma unroll
    for (int k = 0; k < DD; ++k) w3c[k] = Wm[(128+k)*DD + lane];

    const float we0 = We[0*DD+lane], we1 = We[1*DD+lane];
    const float we2 = We[2*DD+lane], we3 = We[3*DD+lane];

    // base_b[lane] = sum_k h_b[k] * (W_msg[k][lane] + W_msg[64+k][lane]),
    // h_b[k] = W_species[0][k] + t[b]*W_t[0][k]   (h depends only on batch)
    float base[2];
    #pragma unroll
    for (int b = 0; b < 2; ++b) {
        float tb = t[b];
        float acc = 0.0f;
        for (int k = 0; k < DD; ++k) {
            float hk = Wsp[k] + tb * Wt[k];
            acc += hk * (Wm[k*DD+lane] + Wm[(DD+k)*DD+lane]);
        }
        base[b] = acc;
    }

    for (int e = wid; e < NEDGE; e += nw) {
        int src = ei[e];
        int dst = ei[NEDGE + e];
        int g   = src >> 12;            // src / 4096 -> structure id
        const float* cl = cell + g*9;
        float tj0 = (float)tj[e*3+0];
        float tj1 = (float)tj[e*3+1];
        float tj2 = (float)tj[e*3+2];
        // offsets = to_jimages @ cell[g]   (row-vector times 3x3)
        float o0 = tj0*cl[0] + tj1*cl[3] + tj2*cl[6];
        float o1 = tj0*cl[1] + tj1*cl[4] + tj2*cl[7];
        float o2 = tj0*cl[2] + tj1*cl[5] + tj2*cl[8];
        float ev0 = pos[dst*3+0] - pos[src*3+0] + o0;
        float ev1 = pos[dst*3+1] - pos[src*3+1] + o1;
        float ev2 = pos[dst*3+2] - pos[src*3+2] + o2;
        float len = sqrtf(ev0*ev0 + ev1*ev1 + ev2*ev2 + 1e-12f);

        // ea[lane] = silu(edge_attr @ W_edge)[lane]
        float ea = silu_f(ev0*we0 + ev1*we1 + ev2*we2 + len*we3);

        // msg[lane] = silu(base_b[lane] + sum_k ea[k]*W3[k][lane])
        float acc = base[g >> 2];       // batch = g / T (T=4)
        unsigned eab = __float_as_uint(ea);
        #pragma unroll
        for (int k = 0; k < DD; ++k) {
            float eak = __uint_as_float(__builtin_amdgcn_readlane(eab, k));
            acc = fmaf(eak, w3c[k], acc);
        }
        float msg = silu_f(acc);

        if (PASS == 1) {
            atomicAdd(&agg[dst*DD + lane], msg);   // coalesced 64-lane atomic
        } else {
            float p = msg * gbuf[dst*DD + lane];
            #pragma unroll
            for (int off = 32; off > 0; off >>= 1)
                p += __shfl_xor(p, off, 64);
            if (lane < 3) {
                float evc = lane == 0 ? ev0 : (lane == 1 ? ev1 : ev2);
                atomicAdd(&outacc[dst*3 + lane], evc * p);
            }
        }
    }
}

// Per-node gate: g[n][d] = silu(h_b[d] + silu(agg[n]@W_upd)[d]) * w_dec[d]
// NOTE: writes gbuf in place over agg (each thread reads its agg before the
// write, and cross-lane values are register-held via readlane) -> saves ws.
__global__ __launch_bounds__(256) void k_node(
    float* aggg,             // in: agg, out: gate (aliased on purpose)
    const float* __restrict__ t, const float* __restrict__ Wsp,
    const float* __restrict__ Wt, const float* __restrict__ Wu,
    const float* __restrict__ wdec)
{
    const int lane = threadIdx.x & 63;
    const int wid  = (blockIdx.x * (blockDim.x >> 6)) + (threadIdx.x >> 6);
    const int nw   = gridDim.x * (blockDim.x >> 6);

    float wu[DD];
    #pragma unroll
    for (int k = 0; k < DD; ++k) wu[k] = Wu[k*DD + lane];
    const float wsl = Wsp[lane], wtl = Wt[lane], wd = wdec[lane];
    const float t0 = t[0], t1 = t[1];

    for (int nd = wid; nd < NNODE; nd += nw) {
        float a = aggg[nd*DD + lane];
        unsigned ab = __float_as_uint(a);
        float acc = 0.0f;
        #pragma unroll
        for (int k = 0; k < DD; ++k) {
            float ak = __uint_as_float(__builtin_amdgcn_readlane(ab, k));
            acc = fmaf(ak, wu[k], acc);
        }
        float tb = (nd >> 14) == 0 ? t0 : t1;   // nd / 16384 -> batch
        float hb = wsl + tb * wtl;
        float hn = hb + silu_f(acc);
        aggg[nd*DD + lane] = silu_f(hn) * wd;
    }
}

// out = outacc * v_mask (broadcast over the 3 components)
__global__ __launch_bounds__(256) void k_final(
    const float* __restrict__ outacc, const float* __restrict__ vm,
    float* __restrict__ out)
{
    int i = blockIdx.x * blockDim.x + threadIdx.x;
    if (i < NNODE*3) out[i] = outacc[i] * vm[i/3];
}

extern "C" void kernel_launch(void* const* d_in, const int* in_sizes, int n_in,
                              void* d_out, int out_size, void* d_ws, size_t ws_size,
                              hipStream_t stream) {
    const float* x    = (const float*)d_in[0];
    const float* t    = (const float*)d_in[1];
    const float* cell = (const float*)d_in[2];
    const float* x1   = (const float*)d_in[3];
    const float* vm   = (const float*)d_in[4];
    const float* Wsp  = (const float*)d_in[5];
    const float* Wt   = (const float*)d_in[6];
    const float* We   = (const float*)d_in[7];
    const float* Wm   = (const float*)d_in[8];
    const float* Wu   = (const float*)d_in[9];
    const float* wdec = (const float*)d_in[10];
    const int*   ei   = (const int*)d_in[11];
    const int*   tj   = (const int*)d_in[12];
    float* out = (float*)d_out;

    // Workspace layout (floats): pos[98304] | agg/gate[2097152] | outacc[98304]
    float* ws     = (float*)d_ws;
    float* pos    = ws;
    float* agg    = ws + 98304;
    float* outacc = agg + 2097152;

    hipMemsetAsync(agg, 0, 2097152*sizeof(float), stream);
    hipMemsetAsync(outacc, 0, 98304*sizeof(float), stream);

    k_prep<<<128, 256, 0, stream>>>(x, x1, vm, pos);
    k_edge<1><<<2048, 256, 0, stream>>>(ei, tj, pos, cell, t, Wsp, Wt, We, Wm,
                                        agg, nullptr, nullptr);
    k_node<<<2048, 256, 0, stream>>>(agg, t, Wsp, Wt, Wu, wdec);
    k_edge<2><<<2048, 256, 0, stream>>>(ei, tj, pos, cell, t, Wsp, Wt, We, Wm,
                                        nullptr, agg, outacc);
    k_final<<<384, 256, 0, stream>>>(outacc, vm, out);
}

// Round 2
// 208.432 us; speedup vs baseline: 2.4769x; 2.4769x over previous
//
#include <hip/hip_runtime.h>
#include <math.h>

#define NNODE 32768     // B*T*N
#define NEDGE 524288    // NNODE * DEG
#define DD 64           // feature dim D

typedef float  f32x4 __attribute__((ext_vector_type(4)));
typedef short  s16x8 __attribute__((ext_vector_type(8)));

__device__ __forceinline__ float silu_f(float x) {
    return x / (1.0f + __expf(-x));
}
// f32 -> bf16 bits, round-to-nearest-even
__device__ __forceinline__ unsigned short bf16r(float f) {
    unsigned u = __float_as_uint(f);
    unsigned r = (u + 0x7FFFu + ((u >> 16) & 1u)) >> 16;
    return (unsigned short)r;
}

// pos = x * v_mask + x1 * (1 - v_mask)
__global__ __launch_bounds__(256) void k_prep(
    const float* __restrict__ x, const float* __restrict__ x1,
    const float* __restrict__ vm, float* __restrict__ pos)
{
    int i = blockIdx.x * blockDim.x + threadIdx.x;
    if (i < NNODE) {
        float m = vm[i];
        #pragma unroll
        for (int c = 0; c < 3; ++c)
            pos[i*3+c] = x[i*3+c]*m + x1[i*3+c]*(1.0f-m);
    }
}

// base[b][ch] = sum_k h_b[k] * (Wm[k][ch] + Wm[64+k][ch]),  h_b[k]=Wsp[k]+t_b*Wt[k]
__global__ void k_base(const float* __restrict__ Wsp, const float* __restrict__ Wt,
                       const float* __restrict__ Wm, const float* __restrict__ tarr,
                       float* __restrict__ base_ws)
{
    int ch = threadIdx.x;            // 64 threads
    float t0 = tarr[0], t1 = tarr[1];
    float aA = 0.0f, aB = 0.0f;
    for (int k = 0; k < DD; ++k) {
        float w = Wm[k*DD + ch] + Wm[(DD+k)*DD + ch];
        aA = fmaf(Wsp[k] + t0*Wt[k], w, aA);
        aB = fmaf(Wsp[k] + t1*Wt[k], w, aB);
    }
    base_ws[ch]      = aA;
    base_ws[DD + ch] = aB;
}

// MFMA edge kernel: one wave = 64 edges (exactly one chunk; grid sized exactly).
// PASS==1: agg[dst][ch] += msg[ch]   PASS==2: outacc[dst][c] += ev[c]*(msg . g[dst])
template<int PASS>
__global__ __launch_bounds__(256) void k_edge_mfma(
    const int* __restrict__ ei, const int* __restrict__ tj,
    const float* __restrict__ pos, const float* __restrict__ cell,
    const float* __restrict__ We, const float* __restrict__ Wm,
    const float* __restrict__ base_ws,
    float* agg, const float* __restrict__ gbuf, float* __restrict__ outacc)
{
    const int lane = threadIdx.x & 63;
    const int warp = threadIdx.x >> 6;
    const int lo16 = lane & 15;
    const int hi   = lane >> 4;
    const int e0   = (blockIdx.x * 4 + warp) * 64;

    // per-wave LDS: edge4 float4[64] (1024B) | dst int[64] (256B) | ea bf16 64x72 (9216B)
    __shared__ __align__(16) char smem_all[4][10496];
    char* my = smem_all[warp];
    float4*         edge4 = (float4*)my;
    int*            dstl  = (int*)(my + 1024);
    unsigned short* ealds = (unsigned short*)(my + 1280);

    // ---- init: W3 B-fragments (bf16), W_edge column, base vectors ----
    s16x8 bfr[4][2];
    #pragma unroll
    for (int t2 = 0; t2 < 4; ++t2)
        #pragma unroll
        for (int s = 0; s < 2; ++s) {
            s16x8 f;
            #pragma unroll
            for (int j = 0; j < 8; ++j) {
                int k = s*32 + hi*8 + j;
                f[j] = (short)bf16r(Wm[(128 + k)*DD + t2*16 + lo16]);
            }
            bfr[t2][s] = f;
        }
    const float we0 = We[0*DD+lane], we1 = We[1*DD+lane];
    const float we2 = We[2*DD+lane], we3 = We[3*DD+lane];
    float bA0 = base_ws[0*16+lo16],    bA1 = base_ws[1*16+lo16];
    float bA2 = base_ws[2*16+lo16],    bA3 = base_ws[3*16+lo16];
    float bB0 = base_ws[DD+0*16+lo16], bB1 = base_ws[DD+1*16+lo16];
    float bB2 = base_ws[DD+2*16+lo16], bB3 = base_ws[DD+3*16+lo16];

    // ---- phase A: geometry (lane = edge) ----
    const int e   = e0 + lane;
    const int src = ei[e];
    const int dst = ei[NEDGE + e];
    // all 64 edges of a chunk lie in one structure (65536 % 64 == 0)
    const int g = __builtin_amdgcn_readfirstlane(src) >> 12;
    const float* cl = cell + g*9;
    float c00=cl[0],c01=cl[1],c02=cl[2],c10=cl[3],c11=cl[4],c12=cl[5],c20=cl[6],c21=cl[7],c22=cl[8];
    float tj0 = (float)tj[e*3+0], tj1 = (float)tj[e*3+1], tj2 = (float)tj[e*3+2];
    float ev0 = pos[dst*3+0] - pos[src*3+0] + tj0*c00 + tj1*c10 + tj2*c20;
    float ev1 = pos[dst*3+1] - pos[src*3+1] + tj0*c01 + tj1*c11 + tj2*c21;
    float ev2 = pos[dst*3+2] - pos[src*3+2] + tj0*c02 + tj1*c12 + tj2*c22;
    float len = sqrtf(ev0*ev0 + ev1*ev1 + ev2*ev2 + 1e-12f);
    edge4[lane] = (float4){ev0, ev1, ev2, len};
    dstl[lane]  = dst;
    __syncthreads();

    // ---- phase A2: ea tile (lane = channel), bf16, padded stride 72 ----
    #pragma unroll 4
    for (int ee = 0; ee < 64; ++ee) {
        float4 q = edge4[ee];                          // uniform -> broadcast
        float v = q.x*we0 + q.y*we1 + q.z*we2 + q.w*we3;
        ealds[ee*72 + lane] = bf16r(silu_f(v));
    }
    __syncthreads();

    // batch select (uniform per wave)
    const bool sb = (g >> 2) != 0;
    const float bv0 = sb ? bB0 : bA0, bv1 = sb ? bB1 : bA1;
    const float bv2 = sb ? bB2 : bA2, bv3 = sb ? bB3 : bA3;

    // ---- phase C: 4 sub-tiles of 16 edges ----
    #pragma unroll
    for (int i = 0; i < 4; ++i) {
        const unsigned short* arow = ealds + (i*16 + lo16)*72 + hi*8;
        s16x8 a0 = *(const s16x8*)(arow);
        s16x8 a1 = *(const s16x8*)(arow + 32);
        int dr0 = dstl[i*16 + hi*4 + 0];
        int dr1 = dstl[i*16 + hi*4 + 1];
        int dr2 = dstl[i*16 + hi*4 + 2];
        int dr3 = dstl[i*16 + hi*4 + 3];
        float p0 = 0.f, p1 = 0.f, p2 = 0.f, p3 = 0.f;
        #pragma unroll
        for (int t2 = 0; t2 < 4; ++t2) {
            f32x4 acc = {0.f, 0.f, 0.f, 0.f};
            acc = __builtin_amdgcn_mfma_f32_16x16x32_bf16(a0, bfr[t2][0], acc, 0, 0, 0);
            acc = __builtin_amdgcn_mfma_f32_16x16x32_bf16(a1, bfr[t2][1], acc, 0, 0, 0);
            const float bvt = t2==0 ? bv0 : t2==1 ? bv1 : t2==2 ? bv2 : bv3;
            const int   chc = t2*16 + lo16;
            #pragma unroll
            for (int r = 0; r < 4; ++r) {
                const int drr = r==0 ? dr0 : r==1 ? dr1 : r==2 ? dr2 : dr3;
                float msg = silu_f(acc[r] + bvt);
                if (PASS == 1) {
                    atomicAdd(&agg[drr*DD + chc], msg);
                } else {
                    float pm = msg * gbuf[drr*DD + chc];
                    if (r==0) p0 += pm; else if (r==1) p1 += pm;
                    else if (r==2) p2 += pm; else p3 += pm;
                }
            }
        }
        if (PASS == 2) {
            #pragma unroll
            for (int st = 1; st < 16; st <<= 1) {
                p0 += __shfl_xor(p0, st, 64);
                p1 += __shfl_xor(p1, st, 64);
                p2 += __shfl_xor(p2, st, 64);
                p3 += __shfl_xor(p3, st, 64);
            }
            if (lo16 < 12) {
                int rr = lo16 / 3, c = lo16 % 3;
                float dsel = rr==0 ? p0 : rr==1 ? p1 : rr==2 ? p2 : p3;
                int   drow = rr==0 ? dr0 : rr==1 ? dr1 : rr==2 ? dr2 : dr3;
                int   lrow = i*16 + hi*4 + rr;
                float evc = *(const float*)(my + lrow*16 + c*4);
                atomicAdd(&outacc[drow*3 + c], evc * dsel);
            }
        }
    }
}

// Per-node gate: g[n][d] = silu(h_b[d] + silu(agg[n]@W_upd)[d]) * w_dec[d]  (in place)
__global__ __launch_bounds__(256) void k_node(
    float* aggg,
    const float* __restrict__ t, const float* __restrict__ Wsp,
    const float* __restrict__ Wt, const float* __restrict__ Wu,
    const float* __restrict__ wdec)
{
    const int lane = threadIdx.x & 63;
    const int wid  = (blockIdx.x * (blockDim.x >> 6)) + (threadIdx.x >> 6);
    const int nw   = gridDim.x * (blockDim.x >> 6);

    float wu[DD];
    #pragma unroll
    for (int k = 0; k < DD; ++k) wu[k] = Wu[k*DD + lane];
    const float wsl = Wsp[lane], wtl = Wt[lane], wd = wdec[lane];
    const float t0 = t[0], t1 = t[1];

    for (int nd = wid; nd < NNODE; nd += nw) {
        float a = aggg[nd*DD + lane];
        unsigned ab = __float_as_uint(a);
        float acc = 0.0f;
        #pragma unroll
        for (int k = 0; k < DD; ++k) {
            float ak = __uint_as_float(__builtin_amdgcn_readlane(ab, k));
            acc = fmaf(ak, wu[k], acc);
        }
        float tb = (nd >> 14) == 0 ? t0 : t1;
        float hn = wsl + tb * wtl + silu_f(acc);
        aggg[nd*DD + lane] = silu_f(hn) * wd;
    }
}

// out = outacc * v_mask
__global__ __launch_bounds__(256) void k_final(
    const float* __restrict__ outacc, const float* __restrict__ vm,
    float* __restrict__ out)
{
    int i = blockIdx.x * blockDim.x + threadIdx.x;
    if (i < NNODE*3) out[i] = outacc[i] * vm[i/3];
}

extern "C" void kernel_launch(void* const* d_in, const int* in_sizes, int n_in,
                              void* d_out, int out_size, void* d_ws, size_t ws_size,
                              hipStream_t stream) {
    const float* x    = (const float*)d_in[0];
    const float* t    = (const float*)d_in[1];
    const float* cell = (const float*)d_in[2];
    const float* x1   = (const float*)d_in[3];
    const float* vm   = (const float*)d_in[4];
    const float* Wsp  = (const float*)d_in[5];
    const float* Wt   = (const float*)d_in[6];
    const float* We   = (const float*)d_in[7];
    const float* Wm   = (const float*)d_in[8];
    const float* Wu   = (const float*)d_in[9];
    const float* wdec = (const float*)d_in[10];
    const int*   ei   = (const int*)d_in[11];
    const int*   tj   = (const int*)d_in[12];
    float* out = (float*)d_out;

    // ws floats: pos[98304] | agg/gate[2097152] | outacc[98304] | base[128]
    float* ws      = (float*)d_ws;
    float* pos     = ws;
    float* agg     = ws + 98304;
    float* outacc  = agg + 2097152;
    float* base_ws = outacc + 98304;

    hipMemsetAsync(agg, 0, 2097152*sizeof(float), stream);
    hipMemsetAsync(outacc, 0, 98304*sizeof(float), stream);

    k_prep<<<128, 256, 0, stream>>>(x, x1, vm, pos);
    k_base<<<1, 64, 0, stream>>>(Wsp, Wt, Wm, t, base_ws);
    k_edge_mfma<1><<<2048, 256, 0, stream>>>(ei, tj, pos, cell, We, Wm, base_ws,
                                             agg, nullptr, nullptr);
    k_node<<<2048, 256, 0, stream>>>(agg, t, Wsp, Wt, Wu, wdec);
    k_edge_mfma<2><<<2048, 256, 0, stream>>>(ei, tj, pos, cell, We, Wm, base_ws,
                                             nullptr, agg, outacc);
    k_final<<<384, 256, 0, stream>>>(outacc, vm, out);
}

// Round 3
// 191.573 us; speedup vs baseline: 2.6949x; 1.0880x over previous
//
#include <hip/hip_runtime.h>
#include <math.h>

#define NNODE 32768     // B*T*N
#define NEDGE 524288    // NNODE * DEG
#define DD 64           // feature dim D
#define EPS_G 65536     // edges per structure (NEDGE/8)

typedef float  f32x4 __attribute__((ext_vector_type(4)));
typedef short  s16x8 __attribute__((ext_vector_type(8)));

__device__ __forceinline__ float silu_f(float x) {
    return x / (1.0f + __expf(-x));
}
// f32 -> bf16 bits, round-to-nearest-even
__device__ __forceinline__ unsigned short bf16r(float f) {
    unsigned u = __float_as_uint(f);
    unsigned r = (u + 0x7FFFu + ((u >> 16) & 1u)) >> 16;
    return (unsigned short)r;
}

// pos = x * v_mask + x1 * (1 - v_mask)   (XCD-mapped: structure = blockIdx&7)
__global__ __launch_bounds__(256) void k_prep(
    const float* __restrict__ x, const float* __restrict__ x1,
    const float* __restrict__ vm, float* __restrict__ pos)
{
    int g = blockIdx.x & 7;
    int i = g * 4096 + (blockIdx.x >> 3) * 256 + threadIdx.x;   // 128 blocks
    float m = vm[i];
    #pragma unroll
    for (int c = 0; c < 3; ++c)
        pos[i*3+c] = x[i*3+c]*m + x1[i*3+c]*(1.0f-m);
}

// base[b][ch] = sum_k h_b[k] * (Wm[k][ch] + Wm[64+k][ch]),  h_b[k]=Wsp[k]+t_b*Wt[k]
__global__ void k_base(const float* __restrict__ Wsp, const float* __restrict__ Wt,
                       const float* __restrict__ Wm, const float* __restrict__ tarr,
                       float* __restrict__ base_ws)
{
    int ch = threadIdx.x;            // 64 threads
    float t0 = tarr[0], t1 = tarr[1];
    float aA = 0.0f, aB = 0.0f;
    for (int k = 0; k < DD; ++k) {
        float w = Wm[k*DD + ch] + Wm[(DD+k)*DD + ch];
        aA = fmaf(Wsp[k] + t0*Wt[k], w, aA);
        aB = fmaf(Wsp[k] + t1*Wt[k], w, aB);
    }
    base_ws[ch]      = aA;
    base_ws[DD + ch] = aB;
}

// MFMA edge kernel: wave = 64 edges, all within structure g = blockIdx&7 so that
// all atomics/gathers hit the XCD-local L2 slice (1 MB of agg/gbuf per XCD).
// PASS==1: agg[dst][ch] += msg[ch]   PASS==2: outacc[dst][c] += ev[c]*(msg . g[dst])
template<int PASS>
__global__ __launch_bounds__(256, 4) void k_edge_mfma(
    const int* __restrict__ ei, const int* __restrict__ tj,
    const float* __restrict__ pos, const float* __restrict__ cell,
    const float* __restrict__ We, const float* __restrict__ Wm,
    const float* __restrict__ base_ws,
    float* agg, const float* __restrict__ gbuf, float* __restrict__ outacc)
{
    const int lane = threadIdx.x & 63;
    const int warp = threadIdx.x >> 6;
    const int lo16 = lane & 15;
    const int hi   = lane >> 4;
    const int g    = blockIdx.x & 7;          // structure == XCD slot
    const int e0   = g * EPS_G + ((blockIdx.x >> 3) * 4 + warp) * 64;

    // per-wave LDS: edge4 float4[64] (1024B) | dst int[64] (256B) | ea bf16 [16][72] (2304B)
    __shared__ __align__(16) char smem_all[4][3584];
    char* my = smem_all[warp];
    float4*         edge4 = (float4*)my;
    int*            dstl  = (int*)(my + 1024);
    unsigned short* ealds = (unsigned short*)(my + 1280);

    // ---- init: W3 B-fragments (bf16), W_edge column, base vectors ----
    s16x8 bfr[4][2];
    #pragma unroll
    for (int t2 = 0; t2 < 4; ++t2)
        #pragma unroll
        for (int s = 0; s < 2; ++s) {
            s16x8 f;
            #pragma unroll
            for (int j = 0; j < 8; ++j) {
                int k = s*32 + hi*8 + j;
                f[j] = (short)bf16r(Wm[(128 + k)*DD + t2*16 + lo16]);
            }
            bfr[t2][s] = f;
        }
    const float we0 = We[0*DD+lane], we1 = We[1*DD+lane];
    const float we2 = We[2*DD+lane], we3 = We[3*DD+lane];
    const bool  sb  = (g >> 2) != 0;          // batch
    const float bv0 = base_ws[sb*DD + 0*16+lo16];
    const float bv1 = base_ws[sb*DD + 1*16+lo16];
    const float bv2 = base_ws[sb*DD + 2*16+lo16];
    const float bv3 = base_ws[sb*DD + 3*16+lo16];

    // ---- phase A: geometry (lane = edge) ----
    const int e   = e0 + lane;
    const int src = ei[e];
    const int dst = ei[NEDGE + e];
    const float* cl = cell + g*9;
    float c00=cl[0],c01=cl[1],c02=cl[2],c10=cl[3],c11=cl[4],c12=cl[5],c20=cl[6],c21=cl[7],c22=cl[8];
    float tj0 = (float)tj[e*3+0], tj1 = (float)tj[e*3+1], tj2 = (float)tj[e*3+2];
    float ev0 = pos[dst*3+0] - pos[src*3+0] + tj0*c00 + tj1*c10 + tj2*c20;
    float ev1 = pos[dst*3+1] - pos[src*3+1] + tj0*c01 + tj1*c11 + tj2*c21;
    float ev2 = pos[dst*3+2] - pos[src*3+2] + tj0*c02 + tj1*c12 + tj2*c22;
    float len = sqrtf(ev0*ev0 + ev1*ev1 + ev2*ev2 + 1e-12f);
    edge4[lane] = (float4){ev0, ev1, ev2, len};
    dstl[lane]  = dst;

    // ---- 4 sub-tiles of 16 edges: stage ea (lane=channel), then MFMA ----
    #pragma unroll
    for (int i = 0; i < 4; ++i) {
        __syncthreads();     // iter0: edge4 visible; >0: prior a-frag reads done
        #pragma unroll
        for (int ee = 0; ee < 16; ++ee) {
            float4 q = edge4[i*16 + ee];               // uniform -> broadcast
            float v = q.x*we0 + q.y*we1 + q.z*we2 + q.w*we3;
            ealds[ee*72 + lane] = bf16r(silu_f(v));
        }
        __syncthreads();     // ea tile visible

        const unsigned short* arow = ealds + lo16*72 + hi*8;
        s16x8 a0 = *(const s16x8*)(arow);
        s16x8 a1 = *(const s16x8*)(arow + 32);
        int dr0 = dstl[i*16 + hi*4 + 0];
        int dr1 = dstl[i*16 + hi*4 + 1];
        int dr2 = dstl[i*16 + hi*4 + 2];
        int dr3 = dstl[i*16 + hi*4 + 3];
        float p0 = 0.f, p1 = 0.f, p2 = 0.f, p3 = 0.f;
        #pragma unroll
        for (int t2 = 0; t2 < 4; ++t2) {
            f32x4 acc = {0.f, 0.f, 0.f, 0.f};
            acc = __builtin_amdgcn_mfma_f32_16x16x32_bf16(a0, bfr[t2][0], acc, 0, 0, 0);
            acc = __builtin_amdgcn_mfma_f32_16x16x32_bf16(a1, bfr[t2][1], acc, 0, 0, 0);
            const float bvt = t2==0 ? bv0 : t2==1 ? bv1 : t2==2 ? bv2 : bv3;
            const int   chc = t2*16 + lo16;
            #pragma unroll
            for (int r = 0; r < 4; ++r) {
                const int drr = r==0 ? dr0 : r==1 ? dr1 : r==2 ? dr2 : dr3;
                float msg = silu_f(acc[r] + bvt);
                if (PASS == 1) {
                    atomicAdd(&agg[drr*DD + chc], msg);
                } else {
                    float pm = msg * gbuf[drr*DD + chc];
                    if (r==0) p0 += pm; else if (r==1) p1 += pm;
                    else if (r==2) p2 += pm; else p3 += pm;
                }
            }
        }
        if (PASS == 2) {
            #pragma unroll
            for (int st = 1; st < 16; st <<= 1) {
                p0 += __shfl_xor(p0, st, 64);
                p1 += __shfl_xor(p1, st, 64);
                p2 += __shfl_xor(p2, st, 64);
                p3 += __shfl_xor(p3, st, 64);
            }
            if (lo16 < 12) {
                int rr = lo16 / 3, c = lo16 % 3;
                float dsel = rr==0 ? p0 : rr==1 ? p1 : rr==2 ? p2 : p3;
                int   drow = rr==0 ? dr0 : rr==1 ? dr1 : rr==2 ? dr2 : dr3;
                int   lrow = i*16 + hi*4 + rr;
                float evc = *(const float*)(my + lrow*16 + c*4);
                atomicAdd(&outacc[drow*3 + c], evc * dsel);
            }
        }
    }
}

// Per-node gate: g[n][d] = silu(h_b[d] + silu(agg[n]@W_upd)[d]) * w_dec[d]  (in place)
// XCD-mapped so each structure's 1 MB agg slice stays in its XCD L2.
__global__ __launch_bounds__(256) void k_node(
    float* aggg,
    const float* __restrict__ t, const float* __restrict__ Wsp,
    const float* __restrict__ Wt, const float* __restrict__ Wu,
    const float* __restrict__ wdec)
{
    const int lane = threadIdx.x & 63;
    const int warp = threadIdx.x >> 6;
    const int g    = blockIdx.x & 7;
    const int wloc = (blockIdx.x >> 3) * 4 + warp;     // 0..1023 within structure

    float wu[DD];
    #pragma unroll
    for (int k = 0; k < DD; ++k) wu[k] = Wu[k*DD + lane];
    const float wsl = Wsp[lane], wtl = Wt[lane], wd = wdec[lane];
    const float tb = (g >> 2) == 0 ? t[0] : t[1];

    #pragma unroll
    for (int j = 0; j < 4; ++j) {
        int nd = g*4096 + wloc + j*1024;
        float a = aggg[nd*DD + lane];
        unsigned ab = __float_as_uint(a);
        float acc = 0.0f;
        #pragma unroll
        for (int k = 0; k < DD; ++k) {
            float ak = __uint_as_float(__builtin_amdgcn_readlane(ab, k));
            acc = fmaf(ak, wu[k], acc);
        }
        float hn = wsl + tb * wtl + silu_f(acc);
        aggg[nd*DD + lane] = silu_f(hn) * wd;
    }
}

// out = outacc * v_mask  (XCD-mapped)
__global__ __launch_bounds__(256) void k_final(
    const float* __restrict__ outacc, const float* __restrict__ vm,
    float* __restrict__ out)
{
    int g = blockIdx.x & 7;
    int i = g*12288 + (blockIdx.x >> 3)*256 + threadIdx.x;   // 384 blocks
    out[i] = outacc[i] * vm[i/3];
}

extern "C" void kernel_launch(void* const* d_in, const int* in_sizes, int n_in,
                              void* d_out, int out_size, void* d_ws, size_t ws_size,
                              hipStream_t stream) {
    const float* x    = (const float*)d_in[0];
    const float* t    = (const float*)d_in[1];
    const float* cell = (const float*)d_in[2];
    const float* x1   = (const float*)d_in[3];
    const float* vm   = (const float*)d_in[4];
    const float* Wsp  = (const float*)d_in[5];
    const float* Wt   = (const float*)d_in[6];
    const float* We   = (const float*)d_in[7];
    const float* Wm   = (const float*)d_in[8];
    const float* Wu   = (const float*)d_in[9];
    const float* wdec = (const float*)d_in[10];
    const int*   ei   = (const int*)d_in[11];
    const int*   tj   = (const int*)d_in[12];
    float* out = (float*)d_out;

    // ws floats: pos[98304] | agg/gate[2097152] | outacc[98304] | base[128]
    float* ws      = (float*)d_ws;
    float* pos     = ws;
    float* agg     = ws + 98304;
    float* outacc  = agg + 2097152;
    float* base_ws = outacc + 98304;

    hipMemsetAsync(agg, 0, 2097152*sizeof(float), stream);
    hipMemsetAsync(outacc, 0, 98304*sizeof(float), stream);

    k_prep<<<128, 256, 0, stream>>>(x, x1, vm, pos);
    k_base<<<1, 64, 0, stream>>>(Wsp, Wt, Wm, t, base_ws);
    k_edge_mfma<1><<<2048, 256, 0, stream>>>(ei, tj, pos, cell, We, Wm, base_ws,
                                             agg, nullptr, nullptr);
    k_node<<<2048, 256, 0, stream>>>(agg, t, Wsp, Wt, Wu, wdec);
    k_edge_mfma<2><<<2048, 256, 0, stream>>>(ei, tj, pos, cell, We, Wm, base_ws,
                                             nullptr, agg, outacc);
    k_final<<<384, 256, 0, stream>>>(outacc, vm, out);
}